// Round 6
// baseline (293.160 us; speedup 1.0000x reference)
//
#include <hip/hip_runtime.h>
#include <hip/hip_cooperative_groups.h>
#include <cstdint>

namespace cg = cooperative_groups;

// ---------------------------------------------------------------------------
// NeuralODE DoPri5 on MI355X — Round 6: self-validating stamped exchange.
// R5 post-mortem: 2.2 us/stage = 3 serialized coherence round trips (drain,
// stamp, gather). This round fuses them: every exchanged value is a 32-bit
// word [phase16 | f16bits]. Stamp rides in the same 64-bit atomic store as
// the data -> writer needs no drain/stamp/barrier; reader polls the data
// words directly (one round trip). Double-buffer by phase parity guarantees
// stamp==phase is exact; 0xAA poison (0xAAAA stamp) never matches.
// Weights stay LDS-resident: 32 groups x 8 WGs, member m owns hidden slice
// [128m,128m+128); MFMA 16x16x32_f16. Controller: sentinel slots + wave0.
// ---------------------------------------------------------------------------

typedef _Float16 f16x8 __attribute__((ext_vector_type(8)));
typedef float f32x4 __attribute__((ext_vector_type(4)));

#define SMEM_BYTES 152640

// ws: [0, 8KB) errSlots | [8KB, 8KB + 4MB) partB: 2 bufs x 256 WG x 1024 u64
#define PART_OFF 8192u

union H1U { unsigned short u; _Float16 h; };

__device__ __forceinline__ float fast_tanh(float v) {
  float e = __builtin_amdgcn_exp2f(v * 2.88539008177793f);
  return fmaf(-2.0f, __builtin_amdgcn_rcpf(e + 1.0f), 1.0f);
}

__device__ __forceinline__ float f16b(unsigned b) {
  H1U x; x.u = (unsigned short)b; return (float)x.h;
}

extern "C" __global__ void __launch_bounds__(256, 1) neural_ode_dopri5(
    const float* __restrict__ x0g, const float* __restrict__ W1,
    const float* __restrict__ b1, const float* __restrict__ W2,
    const float* __restrict__ b2, float* __restrict__ out,
    unsigned long long* __restrict__ partB, float* __restrict__ errSlots) {
  cg::grid_group gridg = cg::this_grid();
  const int tid = threadIdx.x;
  const int bx = blockIdx.x;
  const int g = bx & 31;   // group: rows [8g, 8g+8)
  const int m = bx >> 5;   // member: hidden slice [128m, 128m+128)
  const int w = tid >> 6, lane = tid & 63, n16 = lane & 15, q = lane >> 4;
  const int r = tid >> 5, fb = tid & 31;  // thread state: row r, feats [8fb,8fb+8)

  // ---- LDS carve (dynamic, ~149 KB) --------------------------------------
  extern __shared__ char smem[];
  _Float16* W1s  = (_Float16*)smem;                  // [128 cols][264]
  _Float16* W2s  = (_Float16*)(smem + 67584);        // [256 cols][136]
  _Float16* xi_s = (_Float16*)(smem + 137216);       // [16 rows][264]; rows0-7 reused as stag
  _Float16* h_s  = (_Float16*)(smem + 145664);       // [16 rows][136]
  float* sw1t   = (float*)(smem + 150016);           // [128]
  float* sb1c   = sw1t + 128;                        // [128]
  float* sbias1 = sb1c + 128;                        // [128]
  float* sb2    = sbias1 + 128;                      // [256]
  float* sred   = sb2 + 256;                         // [4]
  float* sbc    = sred + 4;                          // [1] controller broadcast

  // ---- prologue ----------------------------------------------------------
  if (bx == 0)
    for (int i = tid; i < 2048; i += 256) errSlots[i] = -1.0f;  // sentinel
  for (int kk = 0; kk < 128; ++kk) {
    const int k = 2 * kk + (tid >> 7), c = tid & 127;
    W1s[c * 264 + k] = (_Float16)W1[k * 1024 + m * 128 + c];
  }
  for (int kk = 0; kk < 128; ++kk)
    W2s[tid * 136 + kk] = (_Float16)W2[(m * 128 + kk) * 256 + tid];
  if (tid < 128) {
    sw1t[tid] = W1[256 * 1024 + m * 128 + tid];
    sb1c[tid] = b1[m * 128 + tid];
  }
  sb2[tid] = b2[tid];
  for (int i = tid; i < 16 * 264; i += 256) xi_s[i] = (_Float16)0.0f;
  for (int i = tid; i < 16 * 136; i += 256) h_s[i] = (_Float16)0.0f;
  gridg.sync();

  // ---- per-thread ODE state ----------------------------------------------
  const float* xrow = x0g + (8 * g + r) * 256 + fb * 8;
  float x[8];
  {
    float4 v0 = ((const float4*)xrow)[0], v1 = ((const float4*)xrow)[1];
    x[0] = v0.x; x[1] = v0.y; x[2] = v0.z; x[3] = v0.w;
    x[4] = v1.x; x[5] = v1.y; x[6] = v1.z; x[7] = v1.w;
  }
  float ks[7][8];
  unsigned phase = 0;  // max 1 + 64*6 = 385 << 0xAAAA poison stamp

  // ---- one vf eval: xi(8 regs/thread) -> k(8 regs/thread) ----------------
  auto stage_eval = [&](const float* xi, float ti, float* kout) {
    ++phase;
    const unsigned buf = phase & 1u;
    if (tid < 128) sbias1[tid] = fmaf(ti, sw1t[tid], sb1c[tid]);
    f16x8 xv;
#pragma unroll
    for (int j = 0; j < 8; ++j) xv[j] = (_Float16)xi[j];
    *(f16x8*)(xi_s + r * 264 + fb * 8) = xv;
    __syncthreads();

    // GEMM1: h_pre[16][128] = xi @ W1slice + bias1
    f32x4 acc1[2];
#pragma unroll
    for (int tt = 0; tt < 2; ++tt) {
      const float bb = sbias1[(2 * w + tt) * 16 + n16];
      acc1[tt] = (f32x4){bb, bb, bb, bb};
    }
#pragma unroll
    for (int kk = 0; kk < 8; ++kk) {
      const f16x8 av = *(const f16x8*)(xi_s + n16 * 264 + kk * 32 + q * 8);
#pragma unroll
      for (int tt = 0; tt < 2; ++tt) {
        const f16x8 bv =
            *(const f16x8*)(W1s + ((2 * w + tt) * 16 + n16) * 264 + kk * 32 + q * 8);
        acc1[tt] = __builtin_amdgcn_mfma_f32_16x16x32_f16(av, bv, acc1[tt], 0, 0, 0);
      }
    }
#pragma unroll
    for (int tt = 0; tt < 2; ++tt) {
      const int c = (2 * w + tt) * 16 + n16;
#pragma unroll
      for (int reg = 0; reg < 4; ++reg)
        h_s[(q * 4 + reg) * 136 + c] = (_Float16)fast_tanh(acc1[tt][reg]);
    }
    __syncthreads();

    // GEMM2 partial: kp[16][256] = h @ W2slice (bias added by reader)
    f32x4 acc2[4];
#pragma unroll
    for (int tt = 0; tt < 4; ++tt) acc2[tt] = (f32x4){0.f, 0.f, 0.f, 0.f};
#pragma unroll
    for (int kk = 0; kk < 4; ++kk) {
      const f16x8 av = *(const f16x8*)(h_s + n16 * 136 + kk * 32 + q * 8);
#pragma unroll
      for (int tt = 0; tt < 4; ++tt) {
        const f16x8 bv =
            *(const f16x8*)(W2s + ((w * 4 + tt) * 16 + n16) * 136 + kk * 32 + q * 8);
        acc2[tt] = __builtin_amdgcn_mfma_f32_16x16x32_f16(av, bv, acc2[tt], 0, 0, 0);
      }
    }
    // transpose fragments -> row-major f16 staging in LDS (reuse xi_s rows0-7)
    _Float16* stag = xi_s;
    if (q < 2) {
#pragma unroll
      for (int tt = 0; tt < 4; ++tt) {
        const int c = (w * 4 + tt) * 16 + n16;
#pragma unroll
        for (int reg = 0; reg < 4; ++reg)
          stag[(q * 4 + reg) * 264 + c] = (_Float16)acc2[tt][reg];
      }
    }
    __syncthreads();  // stag complete

    // publish: 8 values as 8x u32 [phase16|f16] in 4 relaxed u64 stores.
    // Stamp rides with the data -> no drain, no stamp store, no barrier.
    {
      const unsigned long long* srcp =
          (const unsigned long long*)(stag + r * 264 + fb * 8);
      const unsigned long long s0 = srcp[0], s1 = srcp[1];
      const unsigned long long st2 =
          ((unsigned long long)phase << 48) | ((unsigned long long)phase << 16);
      const unsigned long long w0 =
          (s0 & 0xFFFFull) | (((s0 >> 16) & 0xFFFFull) << 32) | st2;
      const unsigned long long w1 =
          ((s0 >> 32) & 0xFFFFull) | (((s0 >> 48) & 0xFFFFull) << 32) | st2;
      const unsigned long long w2 =
          (s1 & 0xFFFFull) | (((s1 >> 16) & 0xFFFFull) << 32) | st2;
      const unsigned long long w3 =
          ((s1 >> 32) & 0xFFFFull) | (((s1 >> 48) & 0xFFFFull) << 32) | st2;
      unsigned long long* dst =
          partB + ((((buf << 8) + bx) << 10) + (r << 7) + (fb << 2));
      __hip_atomic_store(dst + 0, w0, __ATOMIC_RELAXED, __HIP_MEMORY_SCOPE_AGENT);
      __hip_atomic_store(dst + 1, w1, __ATOMIC_RELAXED, __HIP_MEMORY_SCOPE_AGENT);
      __hip_atomic_store(dst + 2, w2, __ATOMIC_RELAXED, __HIP_MEMORY_SCOPE_AGENT);
      __hip_atomic_store(dst + 3, w3, __ATOMIC_RELAXED, __HIP_MEMORY_SCOPE_AGENT);
    }

    // gather: poll the self-validating words of each member; accumulate as
    // members complete (per-member done mask). One coherence round trip.
    float kacc[8];
    {
      const float4* sb2v = (const float4*)(sb2 + fb * 8);
      float4 bA = sb2v[0], bB = sb2v[1];
      kacc[0] = bA.x; kacc[1] = bA.y; kacc[2] = bA.z; kacc[3] = bA.w;
      kacc[4] = bB.x; kacc[5] = bB.y; kacc[6] = bB.z; kacc[7] = bB.w;
    }
    const unsigned ph = phase;
    unsigned pend = 0xFFu;
    do {
#pragma unroll
      for (int mm = 0; mm < 8; ++mm) {
        if (!(pend & (1u << mm))) continue;
        const unsigned long long* pp =
            partB +
            ((((buf << 8) + (mm << 5) + g) << 10) + (r << 7) + (fb << 2));
        const unsigned long long a0 =
            __hip_atomic_load(pp + 0, __ATOMIC_RELAXED, __HIP_MEMORY_SCOPE_AGENT);
        const unsigned long long a1 =
            __hip_atomic_load(pp + 1, __ATOMIC_RELAXED, __HIP_MEMORY_SCOPE_AGENT);
        const unsigned long long a2 =
            __hip_atomic_load(pp + 2, __ATOMIC_RELAXED, __HIP_MEMORY_SCOPE_AGENT);
        const unsigned long long a3 =
            __hip_atomic_load(pp + 3, __ATOMIC_RELAXED, __HIP_MEMORY_SCOPE_AGENT);
        const bool ok = (((unsigned)(a0 >> 16) & 0xFFFFu) == ph) &
                        ((unsigned)(a0 >> 48) == ph) &
                        (((unsigned)(a1 >> 16) & 0xFFFFu) == ph) &
                        ((unsigned)(a1 >> 48) == ph) &
                        (((unsigned)(a2 >> 16) & 0xFFFFu) == ph) &
                        ((unsigned)(a2 >> 48) == ph) &
                        (((unsigned)(a3 >> 16) & 0xFFFFu) == ph) &
                        ((unsigned)(a3 >> 48) == ph);
        if (ok) {
          kacc[0] += f16b((unsigned)a0 & 0xFFFFu);
          kacc[1] += f16b((unsigned)(a0 >> 32) & 0xFFFFu);
          kacc[2] += f16b((unsigned)a1 & 0xFFFFu);
          kacc[3] += f16b((unsigned)(a1 >> 32) & 0xFFFFu);
          kacc[4] += f16b((unsigned)a2 & 0xFFFFu);
          kacc[5] += f16b((unsigned)(a2 >> 32) & 0xFFFFu);
          kacc[6] += f16b((unsigned)a3 & 0xFFFFu);
          kacc[7] += f16b((unsigned)(a3 >> 32) & 0xFFFFu);
          pend &= ~(1u << mm);
        }
      }
    } while (pend);
#pragma unroll
    for (int j = 0; j < 8; ++j) kout[j] = kacc[j];
  };

  // ---- Butcher tableau ----------------------------------------------------
  const float AB[6][6] = {
      {(float)(1.0 / 5.0), 0, 0, 0, 0, 0},
      {(float)(3.0 / 40.0), (float)(9.0 / 40.0), 0, 0, 0, 0},
      {(float)(44.0 / 45.0), (float)(-56.0 / 15.0), (float)(32.0 / 9.0), 0, 0, 0},
      {(float)(19372.0 / 6561.0), (float)(-25360.0 / 2187.0),
       (float)(64448.0 / 6561.0), (float)(-212.0 / 729.0), 0, 0},
      {(float)(9017.0 / 3168.0), (float)(-355.0 / 33.0),
       (float)(46732.0 / 5247.0), (float)(49.0 / 176.0),
       (float)(-5103.0 / 18656.0), 0},
      {(float)(35.0 / 384.0), 0.0f, (float)(500.0 / 1113.0),
       (float)(125.0 / 192.0), (float)(-2187.0 / 6784.0), (float)(11.0 / 84.0)}};
  const float CC[7] = {0.0f, (float)(1.0 / 5.0), (float)(3.0 / 10.0),
                       (float)(4.0 / 5.0), (float)(8.0 / 9.0), 1.0f, 1.0f};
  const float DD[7] = {(float)(35.0 / 384.0 - 5179.0 / 57600.0), 0.0f,
                       (float)(500.0 / 1113.0 - 7571.0 / 16695.0),
                       (float)(125.0 / 192.0 - 393.0 / 640.0),
                       (float)(-2187.0 / 6784.0 + 92097.0 / 339200.0),
                       (float)(11.0 / 84.0 - 187.0 / 2100.0),
                       (float)(-1.0 / 40.0)};

  float t = 0.0f, dt = 0.05f;
  stage_eval(x, 0.0f, ks[0]);  // FSAL seed

  for (int it = 0; it < 64; ++it) {
    if (t >= 1.0f) break;  // controller is globally uniform -> exact
    const float dt_c = fmaxf(fminf(dt, 1.0f - t), 0.0f);

    float x5[8];
#pragma unroll
    for (int s = 1; s <= 6; ++s) {
      float xi[8];
#pragma unroll
      for (int j = 0; j < 8; ++j) {
        float v = x[j];
#pragma unroll
        for (int p = 0; p < 6; ++p)
          if (p < s) v = fmaf(dt_c * AB[s - 1][p], ks[p][j], v);
        xi[j] = v;
        if (s == 6) x5[j] = v;  // stage-7 point == x5 (FSAL)
      }
      stage_eval(xi, fmaf(CC[s], dt_c, t), ks[s]);
    }

    // member 0 of each group publishes its group's err sum to a slot
    if (m == 0) {
      float loc = 0.0f;
#pragma unroll
      for (int j = 0; j < 8; ++j) {
        float e = 0.0f;
#pragma unroll
        for (int s = 0; s < 7; ++s) e = fmaf(dt_c * DD[s], ks[s][j], e);
        const float scale = fmaf(1e-3f, fmaxf(fabsf(x[j]), fabsf(x5[j])), 1e-4f);
        const float rr = e / scale;
        loc = fmaf(rr, rr, loc);
      }
#pragma unroll
      for (int o = 32; o > 0; o >>= 1) loc += __shfl_down(loc, o);
      if (lane == 0) sred[w] = loc;
      __syncthreads();
      if (tid == 0) {
        const float s4 = sred[0] + sred[1] + sred[2] + sred[3];
        __hip_atomic_store(&errSlots[it * 32 + g], s4, __ATOMIC_RELAXED,
                           __HIP_MEMORY_SCOPE_AGENT);
      }
    }
    // wave 0 polls the 32 slots (sentinel: poison/init are negative)
    if (w == 0) {
      for (;;) {
        float v = 0.0f;
        bool okl = true;
        if (lane < 32) {
          v = __hip_atomic_load(&errSlots[it * 32 + lane], __ATOMIC_RELAXED,
                                __HIP_MEMORY_SCOPE_AGENT);
          okl = (v >= 0.0f);
        }
        if (__all(okl)) {
#pragma unroll
          for (int o = 32; o > 0; o >>= 1) v += __shfl_down(v, o);
          if (lane == 0) sbc[0] = v;
          break;
        }
      }
    }
    __syncthreads();
    const float total = sbc[0];
    const float err_norm = sqrtf(total * (1.0f / 65536.0f));
    const bool accept = err_norm <= 1.0f;
    float factor = 0.9f * powf(err_norm + 1e-10f, -0.2f);
    factor = fminf(fmaxf(factor, 0.2f), 5.0f);
    if (accept) {
      t = t + dt_c;
#pragma unroll
      for (int j = 0; j < 8; ++j) { x[j] = x5[j]; ks[0][j] = ks[6][j]; }
    }
    dt = dt_c * factor;
  }

  // ---- output: stack([x0, xf]) (member 0 only) ---------------------------
  if (m == 0) {
    float4* o0 = (float4*)(out + (8 * g + r) * 256 + fb * 8);
    const float4* xr = (const float4*)xrow;
    o0[0] = xr[0]; o0[1] = xr[1];
    float4 a0, a1;
    a0.x = x[0]; a0.y = x[1]; a0.z = x[2]; a0.w = x[3];
    a1.x = x[4]; a1.y = x[5]; a1.z = x[6]; a1.w = x[7];
    float4* o1 = (float4*)(out + 65536 + (8 * g + r) * 256 + fb * 8);
    o1[0] = a0; o1[1] = a1;
  }
}

extern "C" void kernel_launch(void* const* d_in, const int* in_sizes, int n_in,
                              void* d_out, int out_size, void* d_ws,
                              size_t ws_size, hipStream_t stream) {
  const float* x0 = (const float*)d_in[0];
  const float* W1 = (const float*)d_in[1];
  const float* b1 = (const float*)d_in[2];
  const float* W2 = (const float*)d_in[3];
  const float* b2 = (const float*)d_in[4];
  float* out = (float*)d_out;
  char* ws = (char*)d_ws;
  float* errSlots = (float*)ws;
  unsigned long long* partB = (unsigned long long*)(ws + PART_OFF);

  hipFuncSetAttribute((const void*)neural_ode_dopri5,
                      hipFuncAttributeMaxDynamicSharedMemorySize, SMEM_BYTES);

  void* args[] = {&x0, &W1, &b1, &W2, &b2, &out, &partB, &errSlots};
  hipLaunchCooperativeKernel((void*)neural_ode_dopri5, dim3(256), dim3(256),
                             args, SMEM_BYTES, stream);
}

// Round 7
// 240.462 us; speedup vs baseline: 1.2192x; 1.2192x over previous
//
#include <hip/hip_runtime.h>
#include <hip/hip_cooperative_groups.h>
#include <cstdint>

namespace cg = cooperative_groups;

// ---------------------------------------------------------------------------
// NeuralODE DoPri5 on MI355X — Round 7: R5 protocol + per-wave stamps.
// R6 post-mortem: fused detect+gather multiplied poll traffic (every thread
// polling 256B of remote data) -> coherence-point queueing, 1.6 us/stage
// REGRESSION. Revert to R5 (cheap one-line stamp detect + single gather),
// then cut R5's two post-publish WG barriers: each wave drains its own
// stores (inline s_waitcnt vmcnt(0)), stamps its own slot, polls the group's
// 32-stamp line, and gathers — all without __syncthreads. Stage-entry LDS
// barriers re-sync the WG. stag gets a dedicated LDS region (wave skew).
// Weights LDS-resident: 32 groups x 8 WGs, member m owns hidden slice
// [128m,128m+128); MFMA 16x16x32_f16; f16 partials, double-buffered parity.
// ---------------------------------------------------------------------------

typedef _Float16 f16x8 __attribute__((ext_vector_type(8)));
typedef float f32x4 __attribute__((ext_vector_type(4)));

#define SMEM_BYTES 156832

// ws: [0,2MB) f16 partials (2 bufs x 256 WG x 4KB)
//     2MB: stamps (32 groups x 32 u32 = 4KB) | +4KB: errSlots (2048 f32)
#define STAMP_OFF (2u * 1024u * 1024u)
#define SLOT_OFF  (STAMP_OFF + 4096u)

union U64H4 { unsigned long long u; _Float16 h[4]; };

__device__ __forceinline__ float fast_tanh(float v) {
  float e = __builtin_amdgcn_exp2f(v * 2.88539008177793f);
  return fmaf(-2.0f, __builtin_amdgcn_rcpf(e + 1.0f), 1.0f);
}

extern "C" __global__ void __launch_bounds__(256, 1) neural_ode_dopri5(
    const float* __restrict__ x0g, const float* __restrict__ W1,
    const float* __restrict__ b1, const float* __restrict__ W2,
    const float* __restrict__ b2, float* __restrict__ out,
    unsigned long long* __restrict__ partB, unsigned* __restrict__ stamps,
    float* __restrict__ errSlots) {
  cg::grid_group gridg = cg::this_grid();
  const int tid = threadIdx.x;
  const int bx = blockIdx.x;
  const int g = bx & 31;   // group: rows [8g, 8g+8)
  const int m = bx >> 5;   // member: hidden slice [128m, 128m+128)
  const int w = tid >> 6, lane = tid & 63, n16 = lane & 15, q = lane >> 4;
  const int r = tid >> 5, fb = tid & 31;  // thread state: row r, feats [8fb,8fb+8)

  // ---- LDS carve (dynamic, ~153 KB) --------------------------------------
  extern __shared__ char smem[];
  _Float16* W1s  = (_Float16*)smem;                  // [128 cols][264]
  _Float16* W2s  = (_Float16*)(smem + 67584);        // [256 cols][136]
  _Float16* xi_s = (_Float16*)(smem + 137216);       // [16 rows][264]
  _Float16* h_s  = (_Float16*)(smem + 145664);       // [16 rows][136]
  _Float16* stag = (_Float16*)(smem + 150016);       // [8 rows][264] publish staging
  float* sw1t   = (float*)(smem + 154240);           // [128]
  float* sb1c   = sw1t + 128;                        // [128]
  float* sbias1 = sb1c + 128;                        // [128]
  float* sb2    = sbias1 + 128;                      // [256]
  float* sred   = sb2 + 256;                         // [4]

  // ---- prologue ----------------------------------------------------------
  if (bx == 0) {
    for (int i = tid; i < 1024; i += 256) stamps[i] = 0u;        // < 1
    for (int i = tid; i < 2048; i += 256) errSlots[i] = -1.0f;   // sentinel
  }
  for (int kk = 0; kk < 128; ++kk) {
    const int k = 2 * kk + (tid >> 7), c = tid & 127;
    W1s[c * 264 + k] = (_Float16)W1[k * 1024 + m * 128 + c];
  }
  for (int kk = 0; kk < 128; ++kk)
    W2s[tid * 136 + kk] = (_Float16)W2[(m * 128 + kk) * 256 + tid];
  if (tid < 128) {
    sw1t[tid] = W1[256 * 1024 + m * 128 + tid];
    sb1c[tid] = b1[m * 128 + tid];
  }
  sb2[tid] = b2[tid];
  for (int i = tid; i < 16 * 264; i += 256) xi_s[i] = (_Float16)0.0f;
  for (int i = tid; i < 16 * 136; i += 256) h_s[i] = (_Float16)0.0f;
  gridg.sync();

  // ---- per-thread ODE state ----------------------------------------------
  const float* xrow = x0g + (8 * g + r) * 256 + fb * 8;
  float x[8];
  {
    float4 v0 = ((const float4*)xrow)[0], v1 = ((const float4*)xrow)[1];
    x[0] = v0.x; x[1] = v0.y; x[2] = v0.z; x[3] = v0.w;
    x[4] = v1.x; x[5] = v1.y; x[6] = v1.z; x[7] = v1.w;
  }
  float ks[7][8];
  unsigned phase = 0;  // max 385

  // ---- one vf eval: xi(8 regs/thread) -> k(8 regs/thread) ----------------
  auto stage_eval = [&](const float* xi, float ti, float* kout) {
    ++phase;
    const unsigned buf = phase & 1u;
    if (tid < 128) sbias1[tid] = fmaf(ti, sw1t[tid], sb1c[tid]);
    f16x8 xv;
#pragma unroll
    for (int j = 0; j < 8; ++j) xv[j] = (_Float16)xi[j];
    *(f16x8*)(xi_s + r * 264 + fb * 8) = xv;
    __syncthreads();  // stage-entry sync: xi + sbias1 visible; re-syncs skew

    // GEMM1: h_pre[16][128] = xi @ W1slice + bias1
    f32x4 acc1[2];
#pragma unroll
    for (int tt = 0; tt < 2; ++tt) {
      const float bb = sbias1[(2 * w + tt) * 16 + n16];
      acc1[tt] = (f32x4){bb, bb, bb, bb};
    }
#pragma unroll
    for (int kk = 0; kk < 8; ++kk) {
      const f16x8 av = *(const f16x8*)(xi_s + n16 * 264 + kk * 32 + q * 8);
#pragma unroll
      for (int tt = 0; tt < 2; ++tt) {
        const f16x8 bv =
            *(const f16x8*)(W1s + ((2 * w + tt) * 16 + n16) * 264 + kk * 32 + q * 8);
        acc1[tt] = __builtin_amdgcn_mfma_f32_16x16x32_f16(av, bv, acc1[tt], 0, 0, 0);
      }
    }
#pragma unroll
    for (int tt = 0; tt < 2; ++tt) {
      const int c = (2 * w + tt) * 16 + n16;
#pragma unroll
      for (int reg = 0; reg < 4; ++reg)
        h_s[(q * 4 + reg) * 136 + c] = (_Float16)fast_tanh(acc1[tt][reg]);
    }
    __syncthreads();

    // GEMM2 partial: kp[16][256] = h @ W2slice (bias added by reader)
    f32x4 acc2[4];
#pragma unroll
    for (int tt = 0; tt < 4; ++tt) acc2[tt] = (f32x4){0.f, 0.f, 0.f, 0.f};
#pragma unroll
    for (int kk = 0; kk < 4; ++kk) {
      const f16x8 av = *(const f16x8*)(h_s + n16 * 136 + kk * 32 + q * 8);
#pragma unroll
      for (int tt = 0; tt < 4; ++tt) {
        const f16x8 bv =
            *(const f16x8*)(W2s + ((w * 4 + tt) * 16 + n16) * 136 + kk * 32 + q * 8);
        acc2[tt] = __builtin_amdgcn_mfma_f32_16x16x32_f16(av, bv, acc2[tt], 0, 0, 0);
      }
    }
    // transpose fragments -> row-major f16 staging (dedicated region)
    if (q < 2) {
#pragma unroll
      for (int tt = 0; tt < 4; ++tt) {
        const int c = (w * 4 + tt) * 16 + n16;
#pragma unroll
        for (int reg = 0; reg < 4; ++reg)
          stag[(q * 4 + reg) * 264 + c] = (_Float16)acc2[tt][reg];
      }
    }
    __syncthreads();  // stag complete (wave w publishes rows 2w,2w+1)

    // publish this wave's rows: 16 B/thread, relaxed agent stores
    {
      const unsigned long long* srcp =
          (const unsigned long long*)(stag + r * 264 + fb * 8);
      unsigned long long u0 = srcp[0], u1 = srcp[1];
      unsigned long long* dst =
          partB + (buf << 17) + (bx << 9) + (r << 6) + (fb << 1);
      __hip_atomic_store(dst, u0, __ATOMIC_RELAXED, __HIP_MEMORY_SCOPE_AGENT);
      __hip_atomic_store(dst + 1, u1, __ATOMIC_RELAXED, __HIP_MEMORY_SCOPE_AGENT);
    }
    // wave-local drain: this wave's stores are acked at the coherence point
    asm volatile("s_waitcnt vmcnt(0)" ::: "memory");
    // per-wave stamp: visibility implies this wave's rows are visible
    if (lane == 0)
      __hip_atomic_store(&stamps[g * 32 + m * 4 + w], phase, __ATOMIC_RELAXED,
                         __HIP_MEMORY_SCOPE_AGENT);
    // per-wave poll of the group's 32 stamps (one 128B region, lanes 0..31)
    for (;;) {
      unsigned v = phase;
      if (lane < 32)
        v = __hip_atomic_load(&stamps[g * 32 + lane], __ATOMIC_RELAXED,
                              __HIP_MEMORY_SCOPE_AGENT);
      if (__all(v >= phase)) break;
    }
    // gather: issue all 16 loads, then sum (+b2)
    unsigned long long va[8][2];
    const int gbase = (buf << 17) + (r << 6) + (fb << 1);
#pragma unroll
    for (int mm = 0; mm < 8; ++mm) {
      const unsigned long long* pp = partB + gbase + ((mm * 32 + g) << 9);
      va[mm][0] = __hip_atomic_load(pp, __ATOMIC_RELAXED, __HIP_MEMORY_SCOPE_AGENT);
      va[mm][1] = __hip_atomic_load(pp + 1, __ATOMIC_RELAXED, __HIP_MEMORY_SCOPE_AGENT);
    }
    float kacc[8];
    {
      const float4* sb2v = (const float4*)(sb2 + fb * 8);
      float4 bA = sb2v[0], bB = sb2v[1];
      kacc[0] = bA.x; kacc[1] = bA.y; kacc[2] = bA.z; kacc[3] = bA.w;
      kacc[4] = bB.x; kacc[5] = bB.y; kacc[6] = bB.z; kacc[7] = bB.w;
    }
#pragma unroll
    for (int mm = 0; mm < 8; ++mm) {
      U64H4 ua, ub;
      ua.u = va[mm][0]; ub.u = va[mm][1];
#pragma unroll
      for (int j = 0; j < 4; ++j) {
        kacc[j] += (float)ua.h[j];
        kacc[4 + j] += (float)ub.h[j];
      }
    }
#pragma unroll
    for (int j = 0; j < 8; ++j) kout[j] = kacc[j];
  };

  // ---- Butcher tableau ----------------------------------------------------
  const float AB[6][6] = {
      {(float)(1.0 / 5.0), 0, 0, 0, 0, 0},
      {(float)(3.0 / 40.0), (float)(9.0 / 40.0), 0, 0, 0, 0},
      {(float)(44.0 / 45.0), (float)(-56.0 / 15.0), (float)(32.0 / 9.0), 0, 0, 0},
      {(float)(19372.0 / 6561.0), (float)(-25360.0 / 2187.0),
       (float)(64448.0 / 6561.0), (float)(-212.0 / 729.0), 0, 0},
      {(float)(9017.0 / 3168.0), (float)(-355.0 / 33.0),
       (float)(46732.0 / 5247.0), (float)(49.0 / 176.0),
       (float)(-5103.0 / 18656.0), 0},
      {(float)(35.0 / 384.0), 0.0f, (float)(500.0 / 1113.0),
       (float)(125.0 / 192.0), (float)(-2187.0 / 6784.0), (float)(11.0 / 84.0)}};
  const float CC[7] = {0.0f, (float)(1.0 / 5.0), (float)(3.0 / 10.0),
                       (float)(4.0 / 5.0), (float)(8.0 / 9.0), 1.0f, 1.0f};
  const float DD[7] = {(float)(35.0 / 384.0 - 5179.0 / 57600.0), 0.0f,
                       (float)(500.0 / 1113.0 - 7571.0 / 16695.0),
                       (float)(125.0 / 192.0 - 393.0 / 640.0),
                       (float)(-2187.0 / 6784.0 + 92097.0 / 339200.0),
                       (float)(11.0 / 84.0 - 187.0 / 2100.0),
                       (float)(-1.0 / 40.0)};

  float t = 0.0f, dt = 0.05f;
  stage_eval(x, 0.0f, ks[0]);  // FSAL seed

  for (int it = 0; it < 64; ++it) {
    if (t >= 1.0f) break;  // controller is globally uniform -> exact
    const float dt_c = fmaxf(fminf(dt, 1.0f - t), 0.0f);

    float x5[8];
#pragma unroll
    for (int s = 1; s <= 6; ++s) {
      float xi[8];
#pragma unroll
      for (int j = 0; j < 8; ++j) {
        float v = x[j];
#pragma unroll
        for (int p = 0; p < 6; ++p)
          if (p < s) v = fmaf(dt_c * AB[s - 1][p], ks[p][j], v);
        xi[j] = v;
        if (s == 6) x5[j] = v;  // stage-7 point == x5 (FSAL)
      }
      stage_eval(xi, fmaf(CC[s], dt_c, t), ks[s]);
    }

    // member 0 of each group publishes its group's err sum to a slot
    if (m == 0) {
      float loc = 0.0f;
#pragma unroll
      for (int j = 0; j < 8; ++j) {
        float e = 0.0f;
#pragma unroll
        for (int s = 0; s < 7; ++s) e = fmaf(dt_c * DD[s], ks[s][j], e);
        const float scale = fmaf(1e-3f, fmaxf(fabsf(x[j]), fabsf(x5[j])), 1e-4f);
        const float rr = e / scale;
        loc = fmaf(rr, rr, loc);
      }
#pragma unroll
      for (int o = 32; o > 0; o >>= 1) loc += __shfl_down(loc, o);
      if (lane == 0) sred[w] = loc;
      __syncthreads();
      if (tid == 0) {
        const float s4 = sred[0] + sred[1] + sred[2] + sred[3];
        __hip_atomic_store(&errSlots[it * 32 + g], s4, __ATOMIC_RELAXED,
                           __HIP_MEMORY_SCOPE_AGENT);
      }
    }
    // per-wave poll of the 32 slots (sentinel: poison/init negative)
    float total;
    for (;;) {
      float v = 0.0f;
      bool okl = true;
      if (lane < 32) {
        v = __hip_atomic_load(&errSlots[it * 32 + lane], __ATOMIC_RELAXED,
                              __HIP_MEMORY_SCOPE_AGENT);
        okl = (v >= 0.0f);
      }
      if (__all(okl)) {
        float s = v;
#pragma unroll
        for (int o = 32; o > 0; o >>= 1) s += __shfl_down(s, o);
        total = __shfl(s, 0);
        break;
      }
    }
    const float err_norm = sqrtf(total * (1.0f / 65536.0f));
    const bool accept = err_norm <= 1.0f;
    float factor = 0.9f * powf(err_norm + 1e-10f, -0.2f);
    factor = fminf(fmaxf(factor, 0.2f), 5.0f);
    if (accept) {
      t = t + dt_c;
#pragma unroll
      for (int j = 0; j < 8; ++j) { x[j] = x5[j]; ks[0][j] = ks[6][j]; }
    }
    dt = dt_c * factor;
  }

  // ---- output: stack([x0, xf]) (member 0 only) ---------------------------
  if (m == 0) {
    float4* o0 = (float4*)(out + (8 * g + r) * 256 + fb * 8);
    const float4* xr = (const float4*)xrow;
    o0[0] = xr[0]; o0[1] = xr[1];
    float4 a0, a1;
    a0.x = x[0]; a0.y = x[1]; a0.z = x[2]; a0.w = x[3];
    a1.x = x[4]; a1.y = x[5]; a1.z = x[6]; a1.w = x[7];
    float4* o1 = (float4*)(out + 65536 + (8 * g + r) * 256 + fb * 8);
    o1[0] = a0; o1[1] = a1;
  }
}

extern "C" void kernel_launch(void* const* d_in, const int* in_sizes, int n_in,
                              void* d_out, int out_size, void* d_ws,
                              size_t ws_size, hipStream_t stream) {
  const float* x0 = (const float*)d_in[0];
  const float* W1 = (const float*)d_in[1];
  const float* b1 = (const float*)d_in[2];
  const float* W2 = (const float*)d_in[3];
  const float* b2 = (const float*)d_in[4];
  float* out = (float*)d_out;
  char* ws = (char*)d_ws;
  unsigned long long* partB = (unsigned long long*)ws;
  unsigned* stamps = (unsigned*)(ws + STAMP_OFF);
  float* errSlots = (float*)(ws + SLOT_OFF);

  hipFuncSetAttribute((const void*)neural_ode_dopri5,
                      hipFuncAttributeMaxDynamicSharedMemorySize, SMEM_BYTES);

  void* args[] = {&x0, &W1, &b1, &W2, &b2, &out, &partB, &stamps, &errSlots};
  hipLaunchCooperativeKernel((void*)neural_ode_dopri5, dim3(256), dim3(256),
                             args, SMEM_BYTES, stream);
}

// Round 9
// 228.595 us; speedup vs baseline: 1.2824x; 1.0519x over previous
//
#include <hip/hip_runtime.h>
#include <hip/hip_cooperative_groups.h>
#include <cstdint>

namespace cg = cooperative_groups;

// ---------------------------------------------------------------------------
// NeuralODE DoPri5 on MI355X — Round 9: R5 protocol + barrier trims.
// R8 post-mortem: sc0-only (XCD-local) exchange failed validation — HIP has
// no XCD scope; sc0 load may not bypass L1 (stale parity buffer) — dropped.
// R5's shape is the measured floor for agent-scope exchange; this round
// removes intra-WG serialization around it:
//  (1) per-wave staging + per-wave column-block publish (no stag barrier;
//      early waves' stores overlap late waves' GEMM2),
//  (2) LDS last-arriver counter issues the member stamp (replaces the
//      post-publish __syncthreads; counter visibility => all drains done),
//  (3) stage barriers 5 -> 3.
// Weights LDS-resident: 32 groups x 8 WGs, member m owns hidden slice
// [128m,128m+128); MFMA 16x16x32_f16; f16 partials, parity double-buffer;
// stamp/poll/gather agent-scope relaxed (proven).
// ---------------------------------------------------------------------------

typedef _Float16 f16x8 __attribute__((ext_vector_type(8)));
typedef float f32x4 __attribute__((ext_vector_type(4)));

#define SMEM_BYTES 157248

// ws: [0,2MB) f16 partials (2 bufs x 256 WG x 4KB)
//     2MB: stamps (32 groups x 16 u32, 64B/group) | +4KB: errSlots (2048 f32)
#define STAMP_OFF (2u * 1024u * 1024u)
#define SLOT_OFF  (STAMP_OFF + 4096u)

union U64H4 { unsigned long long u; _Float16 h[4]; };

__device__ __forceinline__ float fast_tanh(float v) {
  float e = __builtin_amdgcn_exp2f(v * 2.88539008177793f);
  return fmaf(-2.0f, __builtin_amdgcn_rcpf(e + 1.0f), 1.0f);
}

extern "C" __global__ void __launch_bounds__(256, 1) neural_ode_dopri5(
    const float* __restrict__ x0g, const float* __restrict__ W1,
    const float* __restrict__ b1, const float* __restrict__ W2,
    const float* __restrict__ b2, float* __restrict__ out,
    unsigned long long* __restrict__ partB, unsigned* __restrict__ stamps,
    float* __restrict__ errSlots) {
  cg::grid_group gridg = cg::this_grid();
  const int tid = threadIdx.x;
  const int bx = blockIdx.x;
  const int g = bx & 31;   // group: rows [8g, 8g+8)
  const int m = bx >> 5;   // member: hidden slice [128m, 128m+128)
  const int w = tid >> 6, lane = tid & 63, n16 = lane & 15, q = lane >> 4;
  const int r = tid >> 5, fb = tid & 31;  // thread state: row r, feats [8fb,8fb+8)

  // ---- LDS carve (dynamic, ~153.6 KB) ------------------------------------
  extern __shared__ char smem[];
  _Float16* W1s  = (_Float16*)smem;                  // [128 cols][264]
  _Float16* W2s  = (_Float16*)(smem + 67584);        // [256 cols][136]
  _Float16* xi_s = (_Float16*)(smem + 137216);       // [16 rows][264]
  _Float16* h_s  = (_Float16*)(smem + 145664);       // [16 rows][136]
  _Float16* stag = (_Float16*)(smem + 150016);       // [4 waves][8 rows][72]
  float* sw1t   = (float*)(smem + 154624);           // [128]
  float* sb1c   = sw1t + 128;                        // [128]
  float* sbias1 = sb1c + 128;                        // [128]
  float* sb2    = sbias1 + 128;                      // [256]
  float* sred   = sb2 + 256;                         // [4]
  float* sbc    = sred + 4;                          // [1] controller broadcast
  unsigned* scount = (unsigned*)(sbc + 1);           // [1] last-arriver counter

  // ---- prologue ----------------------------------------------------------
  if (bx == 0) {
    for (int i = tid; i < 512; i += 256) stamps[i] = 0u;         // < 1
    for (int i = tid; i < 2048; i += 256) errSlots[i] = -1.0f;   // sentinel
  }
  if (tid == 0) *scount = 0u;
  for (int kk = 0; kk < 128; ++kk) {
    const int k = 2 * kk + (tid >> 7), c = tid & 127;
    W1s[c * 264 + k] = (_Float16)W1[k * 1024 + m * 128 + c];
  }
  for (int kk = 0; kk < 128; ++kk)
    W2s[tid * 136 + kk] = (_Float16)W2[(m * 128 + kk) * 256 + tid];
  if (tid < 128) {
    sw1t[tid] = W1[256 * 1024 + m * 128 + tid];
    sb1c[tid] = b1[m * 128 + tid];
  }
  sb2[tid] = b2[tid];
  for (int i = tid; i < 16 * 264; i += 256) xi_s[i] = (_Float16)0.0f;
  for (int i = tid; i < 16 * 136; i += 256) h_s[i] = (_Float16)0.0f;
  gridg.sync();

  // ---- per-thread ODE state ----------------------------------------------
  const float* xrow = x0g + (8 * g + r) * 256 + fb * 8;
  float x[8];
  {
    float4 v0 = ((const float4*)xrow)[0], v1 = ((const float4*)xrow)[1];
    x[0] = v0.x; x[1] = v0.y; x[2] = v0.z; x[3] = v0.w;
    x[4] = v1.x; x[5] = v1.y; x[6] = v1.z; x[7] = v1.w;
  }
  float ks[7][8];
  unsigned phase = 0;  // max 385

  // ---- one vf eval: xi(8 regs/thread) -> k(8 regs/thread) ----------------
  auto stage_eval = [&](const float* xi, float ti, float* kout) {
    ++phase;
    const unsigned buf = phase & 1u;
    if (tid < 128) sbias1[tid] = fmaf(ti, sw1t[tid], sb1c[tid]);
    f16x8 xv;
#pragma unroll
    for (int j = 0; j < 8; ++j) xv[j] = (_Float16)xi[j];
    *(f16x8*)(xi_s + r * 264 + fb * 8) = xv;
    __syncthreads();  // barrier 1: xi + sbias1 visible

    // GEMM1: h_pre[16][128] = xi @ W1slice + bias1
    f32x4 acc1[2];
#pragma unroll
    for (int tt = 0; tt < 2; ++tt) {
      const float bb = sbias1[(2 * w + tt) * 16 + n16];
      acc1[tt] = (f32x4){bb, bb, bb, bb};
    }
#pragma unroll
    for (int kk = 0; kk < 8; ++kk) {
      const f16x8 av = *(const f16x8*)(xi_s + n16 * 264 + kk * 32 + q * 8);
#pragma unroll
      for (int tt = 0; tt < 2; ++tt) {
        const f16x8 bv =
            *(const f16x8*)(W1s + ((2 * w + tt) * 16 + n16) * 264 + kk * 32 + q * 8);
        acc1[tt] = __builtin_amdgcn_mfma_f32_16x16x32_f16(av, bv, acc1[tt], 0, 0, 0);
      }
    }
#pragma unroll
    for (int tt = 0; tt < 2; ++tt) {
      const int c = (2 * w + tt) * 16 + n16;
#pragma unroll
      for (int reg = 0; reg < 4; ++reg)
        h_s[(q * 4 + reg) * 136 + c] = (_Float16)fast_tanh(acc1[tt][reg]);
    }
    __syncthreads();  // barrier 2: h complete

    // GEMM2 partial: kp[16][256] = h @ W2slice (bias added by reader)
    f32x4 acc2[4];
#pragma unroll
    for (int tt = 0; tt < 4; ++tt) acc2[tt] = (f32x4){0.f, 0.f, 0.f, 0.f};
#pragma unroll
    for (int kk = 0; kk < 4; ++kk) {
      const f16x8 av = *(const f16x8*)(h_s + n16 * 136 + kk * 32 + q * 8);
#pragma unroll
      for (int tt = 0; tt < 4; ++tt) {
        const f16x8 bv =
            *(const f16x8*)(W2s + ((w * 4 + tt) * 16 + n16) * 136 + kk * 32 + q * 8);
        acc2[tt] = __builtin_amdgcn_mfma_f32_16x16x32_f16(av, bv, acc2[tt], 0, 0, 0);
      }
    }
    // wave-synchronous transpose into wave-private staging (NO barrier):
    // wave w covers cols [64w, 64w+64), rows 0..7 (q<2).
    _Float16* stagW = stag + w * (8 * 72);
    if (q < 2) {
#pragma unroll
      for (int tt = 0; tt < 4; ++tt) {
        const int c = tt * 16 + n16;
#pragma unroll
        for (int reg = 0; reg < 4; ++reg)
          stagW[(q * 4 + reg) * 72 + c] = (_Float16)acc2[tt][reg];
      }
    }
    // per-wave publish of its own 64-col block, all 8 rows: 16 B/thread
    {
      const int row = lane >> 3, c8 = lane & 7;
      const unsigned long long* srcp =
          (const unsigned long long*)(stagW + row * 72 + c8 * 8);
      unsigned long long u0 = srcp[0], u1 = srcp[1];
      unsigned long long* dst =
          partB + (buf << 17) + (bx << 9) + (row << 6) + (w << 4) + (c8 << 1);
      __hip_atomic_store(dst, u0, __ATOMIC_RELAXED, __HIP_MEMORY_SCOPE_AGENT);
      __hip_atomic_store(dst + 1, u1, __ATOMIC_RELAXED, __HIP_MEMORY_SCOPE_AGENT);
    }
    // wave-local drain, then LDS last-arriver issues the member stamp.
    asm volatile("s_waitcnt vmcnt(0)" ::: "memory");
    if (lane == 0) {
      const unsigned old = atomicAdd(scount, 1u);
      if (old == 4u * phase - 1u)  // 4th wave: all drains complete
        __hip_atomic_store(&stamps[g * 16 + m], phase, __ATOMIC_RELAXED,
                           __HIP_MEMORY_SCOPE_AGENT);
    }
    // wave 0 polls the group's 8-stamp 64B line
    if (w == 0) {
      for (;;) {
        unsigned v = phase;
        if (lane < 8)
          v = __hip_atomic_load(&stamps[g * 16 + lane], __ATOMIC_RELAXED,
                                __HIP_MEMORY_SCOPE_AGENT);
        if (__all(v >= phase)) break;
      }
    }
    __syncthreads();  // barrier 3: group ready, release all waves

    // gather: issue all 16 loads, then sum (+b2)
    unsigned long long va[8][2];
    const int gbase = (buf << 17) + (r << 6) + (fb << 1);
#pragma unroll
    for (int mm = 0; mm < 8; ++mm) {
      const unsigned long long* pp = partB + gbase + ((mm * 32 + g) << 9);
      va[mm][0] = __hip_atomic_load(pp, __ATOMIC_RELAXED, __HIP_MEMORY_SCOPE_AGENT);
      va[mm][1] = __hip_atomic_load(pp + 1, __ATOMIC_RELAXED, __HIP_MEMORY_SCOPE_AGENT);
    }
    float kacc[8];
    {
      const float4* sb2v = (const float4*)(sb2 + fb * 8);
      float4 bA = sb2v[0], bB = sb2v[1];
      kacc[0] = bA.x; kacc[1] = bA.y; kacc[2] = bA.z; kacc[3] = bA.w;
      kacc[4] = bB.x; kacc[5] = bB.y; kacc[6] = bB.z; kacc[7] = bB.w;
    }
#pragma unroll
    for (int mm = 0; mm < 8; ++mm) {
      U64H4 ua, ub;
      ua.u = va[mm][0]; ub.u = va[mm][1];
#pragma unroll
      for (int j = 0; j < 4; ++j) {
        kacc[j] += (float)ua.h[j];
        kacc[4 + j] += (float)ub.h[j];
      }
    }
#pragma unroll
    for (int j = 0; j < 8; ++j) kout[j] = kacc[j];
  };

  // ---- Butcher tableau ----------------------------------------------------
  const float AB[6][6] = {
      {(float)(1.0 / 5.0), 0, 0, 0, 0, 0},
      {(float)(3.0 / 40.0), (float)(9.0 / 40.0), 0, 0, 0, 0},
      {(float)(44.0 / 45.0), (float)(-56.0 / 15.0), (float)(32.0 / 9.0), 0, 0, 0},
      {(float)(19372.0 / 6561.0), (float)(-25360.0 / 2187.0),
       (float)(64448.0 / 6561.0), (float)(-212.0 / 729.0), 0, 0},
      {(float)(9017.0 / 3168.0), (float)(-355.0 / 33.0),
       (float)(46732.0 / 5247.0), (float)(49.0 / 176.0),
       (float)(-5103.0 / 18656.0), 0},
      {(float)(35.0 / 384.0), 0.0f, (float)(500.0 / 1113.0),
       (float)(125.0 / 192.0), (float)(-2187.0 / 6784.0), (float)(11.0 / 84.0)}};
  const float CC[7] = {0.0f, (float)(1.0 / 5.0), (float)(3.0 / 10.0),
                       (float)(4.0 / 5.0), (float)(8.0 / 9.0), 1.0f, 1.0f};
  const float DD[7] = {(float)(35.0 / 384.0 - 5179.0 / 57600.0), 0.0f,
                       (float)(500.0 / 1113.0 - 7571.0 / 16695.0),
                       (float)(125.0 / 192.0 - 393.0 / 640.0),
                       (float)(-2187.0 / 6784.0 + 92097.0 / 339200.0),
                       (float)(11.0 / 84.0 - 187.0 / 2100.0),
                       (float)(-1.0 / 40.0)};

  float t = 0.0f, dt = 0.05f;
  stage_eval(x, 0.0f, ks[0]);  // FSAL seed

  for (int it = 0; it < 64; ++it) {
    if (t >= 1.0f) break;  // controller is globally uniform -> exact
    const float dt_c = fmaxf(fminf(dt, 1.0f - t), 0.0f);

    float x5[8];
#pragma unroll
    for (int s = 1; s <= 6; ++s) {
      float xi[8];
#pragma unroll
      for (int j = 0; j < 8; ++j) {
        float v = x[j];
#pragma unroll
        for (int p = 0; p < 6; ++p)
          if (p < s) v = fmaf(dt_c * AB[s - 1][p], ks[p][j], v);
        xi[j] = v;
        if (s == 6) x5[j] = v;  // stage-7 point == x5 (FSAL)
      }
      stage_eval(xi, fmaf(CC[s], dt_c, t), ks[s]);
    }

    // member 0 of each group publishes its group's err sum to a slot
    if (m == 0) {
      float loc = 0.0f;
#pragma unroll
      for (int j = 0; j < 8; ++j) {
        float e = 0.0f;
#pragma unroll
        for (int s = 0; s < 7; ++s) e = fmaf(dt_c * DD[s], ks[s][j], e);
        const float scale = fmaf(1e-3f, fmaxf(fabsf(x[j]), fabsf(x5[j])), 1e-4f);
        const float rr = e / scale;
        loc = fmaf(rr, rr, loc);
      }
#pragma unroll
      for (int o = 32; o > 0; o >>= 1) loc += __shfl_down(loc, o);
      if (lane == 0) sred[w] = loc;
      __syncthreads();
      if (tid == 0) {
        const float s4 = sred[0] + sred[1] + sred[2] + sred[3];
        __hip_atomic_store(&errSlots[it * 32 + g], s4, __ATOMIC_RELAXED,
                           __HIP_MEMORY_SCOPE_AGENT);
      }
    }
    // wave 0 polls the 32 slots (sentinel: poison/init negative)
    if (w == 0) {
      for (;;) {
        float v = 0.0f;
        bool okl = true;
        if (lane < 32) {
          v = __hip_atomic_load(&errSlots[it * 32 + lane], __ATOMIC_RELAXED,
                                __HIP_MEMORY_SCOPE_AGENT);
          okl = (v >= 0.0f);
        }
        if (__all(okl)) {
#pragma unroll
          for (int o = 32; o > 0; o >>= 1) v += __shfl_down(v, o);
          if (lane == 0) sbc[0] = v;
          break;
        }
      }
    }
    __syncthreads();
    const float total = sbc[0];
    const float err_norm = sqrtf(total * (1.0f / 65536.0f));
    const bool accept = err_norm <= 1.0f;
    float factor = 0.9f * powf(err_norm + 1e-10f, -0.2f);
    factor = fminf(fmaxf(factor, 0.2f), 5.0f);
    if (accept) {
      t = t + dt_c;
#pragma unroll
      for (int j = 0; j < 8; ++j) { x[j] = x5[j]; ks[0][j] = ks[6][j]; }
    }
    dt = dt_c * factor;
  }

  // ---- output: stack([x0, xf]) (member 0 only) ---------------------------
  if (m == 0) {
    float4* o0 = (float4*)(out + (8 * g + r) * 256 + fb * 8);
    const float4* xr = (const float4*)xrow;
    o0[0] = xr[0]; o0[1] = xr[1];
    float4 a0, a1;
    a0.x = x[0]; a0.y = x[1]; a0.z = x[2]; a0.w = x[3];
    a1.x = x[4]; a1.y = x[5]; a1.z = x[6]; a1.w = x[7];
    float4* o1 = (float4*)(out + 65536 + (8 * g + r) * 256 + fb * 8);
    o1[0] = a0; o1[1] = a1;
  }
}

extern "C" void kernel_launch(void* const* d_in, const int* in_sizes, int n_in,
                              void* d_out, int out_size, void* d_ws,
                              size_t ws_size, hipStream_t stream) {
  const float* x0 = (const float*)d_in[0];
  const float* W1 = (const float*)d_in[1];
  const float* b1 = (const float*)d_in[2];
  const float* W2 = (const float*)d_in[3];
  const float* b2 = (const float*)d_in[4];
  float* out = (float*)d_out;
  char* ws = (char*)d_ws;
  unsigned long long* partB = (unsigned long long*)ws;
  unsigned* stamps = (unsigned*)(ws + STAMP_OFF);
  float* errSlots = (float*)(ws + SLOT_OFF);

  hipFuncSetAttribute((const void*)neural_ode_dopri5,
                      hipFuncAttributeMaxDynamicSharedMemorySize, SMEM_BYTES);

  void* args[] = {&x0, &W1, &b1, &W2, &b2, &out, &partB, &stamps, &errSlots};
  hipLaunchCooperativeKernel((void*)neural_ode_dopri5, dim3(256), dim3(256),
                             args, SMEM_BYTES, stream);
}

// Round 10
// 209.321 us; speedup vs baseline: 1.4005x; 1.0921x over previous
//
#include <hip/hip_runtime.h>
#include <hip/hip_cooperative_groups.h>
#include <cstdint>

namespace cg = cooperative_groups;

// ---------------------------------------------------------------------------
// NeuralODE DoPri5 on MI355X — Round 10: R5 verbatim + paced polling.
// Session law (R6/R7/R9 all regressed): polling that overlaps the store-
// drain window multiplies LLC contention and delays the stores being
// awaited. R5's shape (publish -> WG barrier -> one stamp -> one polling
// wave -> one gather) is the measured optimum. Single change vs R5:
// s_sleep backoff after each FAILED poll round (stamp poll + controller
// poll) — first check immediate, retries paced ~256 cyc, cutting the
// wasted LLC poll stream (FETCH_SIZE 21.5 MB >> 7 MB useful gathers).
// Weights LDS-resident: 32 groups x 8 WGs, member m owns hidden slice
// [128m,128m+128); MFMA 16x16x32_f16; f16 partials, parity double-buffer.
// ---------------------------------------------------------------------------

typedef _Float16 f16x8 __attribute__((ext_vector_type(8)));
typedef float f32x4 __attribute__((ext_vector_type(4)));

#define SMEM_BYTES 152640

// ws: [0,2MB) f16 partials (2 bufs x 256 WG x 4KB)
//     2MB: stamps (32 groups x 16 u32, 64B/group) | +4KB: errSlots (2048 f32)
#define STAMP_OFF (2u * 1024u * 1024u)
#define SLOT_OFF  (STAMP_OFF + 4096u)

union U64H4 { unsigned long long u; _Float16 h[4]; };

__device__ __forceinline__ float fast_tanh(float v) {
  float e = __builtin_amdgcn_exp2f(v * 2.88539008177793f);
  return fmaf(-2.0f, __builtin_amdgcn_rcpf(e + 1.0f), 1.0f);
}

extern "C" __global__ void __launch_bounds__(256, 1) neural_ode_dopri5(
    const float* __restrict__ x0g, const float* __restrict__ W1,
    const float* __restrict__ b1, const float* __restrict__ W2,
    const float* __restrict__ b2, float* __restrict__ out,
    unsigned long long* __restrict__ partB, unsigned* __restrict__ stamps,
    float* __restrict__ errSlots) {
  cg::grid_group gridg = cg::this_grid();
  const int tid = threadIdx.x;
  const int bx = blockIdx.x;
  const int g = bx & 31;   // group: rows [8g, 8g+8)
  const int m = bx >> 5;   // member: hidden slice [128m, 128m+128)
  const int w = tid >> 6, lane = tid & 63, n16 = lane & 15, q = lane >> 4;
  const int r = tid >> 5, fb = tid & 31;  // thread state: row r, feats [8fb,8fb+8)

  // ---- LDS carve (dynamic, ~149 KB) --------------------------------------
  extern __shared__ char smem[];
  _Float16* W1s  = (_Float16*)smem;                  // [128 cols][264]
  _Float16* W2s  = (_Float16*)(smem + 67584);        // [256 cols][136]
  _Float16* xi_s = (_Float16*)(smem + 137216);       // [16 rows][264]; rows0-7 reused as stag
  _Float16* h_s  = (_Float16*)(smem + 145664);       // [16 rows][136]
  float* sw1t   = (float*)(smem + 150016);           // [128]
  float* sb1c   = sw1t + 128;                        // [128]
  float* sbias1 = sb1c + 128;                        // [128]
  float* sb2    = sbias1 + 128;                      // [256]
  float* sred   = sb2 + 256;                         // [4]
  float* sbc    = sred + 4;                          // [1] controller broadcast

  // ---- prologue ----------------------------------------------------------
  if (bx == 0) {
    for (int i = tid; i < 512; i += 256) stamps[i] = 0u;         // < 1
    for (int i = tid; i < 2048; i += 256) errSlots[i] = -1.0f;   // sentinel
  }
  for (int kk = 0; kk < 128; ++kk) {
    const int k = 2 * kk + (tid >> 7), c = tid & 127;
    W1s[c * 264 + k] = (_Float16)W1[k * 1024 + m * 128 + c];
  }
  for (int kk = 0; kk < 128; ++kk)
    W2s[tid * 136 + kk] = (_Float16)W2[(m * 128 + kk) * 256 + tid];
  if (tid < 128) {
    sw1t[tid] = W1[256 * 1024 + m * 128 + tid];
    sb1c[tid] = b1[m * 128 + tid];
  }
  sb2[tid] = b2[tid];
  for (int i = tid; i < 16 * 264; i += 256) xi_s[i] = (_Float16)0.0f;
  for (int i = tid; i < 16 * 136; i += 256) h_s[i] = (_Float16)0.0f;
  gridg.sync();

  // ---- per-thread ODE state ----------------------------------------------
  const float* xrow = x0g + (8 * g + r) * 256 + fb * 8;
  float x[8];
  {
    float4 v0 = ((const float4*)xrow)[0], v1 = ((const float4*)xrow)[1];
    x[0] = v0.x; x[1] = v0.y; x[2] = v0.z; x[3] = v0.w;
    x[4] = v1.x; x[5] = v1.y; x[6] = v1.z; x[7] = v1.w;
  }
  float ks[7][8];
  unsigned phase = 0;  // max 385

  // ---- one vf eval: xi(8 regs/thread) -> k(8 regs/thread) ----------------
  auto stage_eval = [&](const float* xi, float ti, float* kout) {
    ++phase;
    const unsigned buf = phase & 1u;
    if (tid < 128) sbias1[tid] = fmaf(ti, sw1t[tid], sb1c[tid]);
    f16x8 xv;
#pragma unroll
    for (int j = 0; j < 8; ++j) xv[j] = (_Float16)xi[j];
    *(f16x8*)(xi_s + r * 264 + fb * 8) = xv;
    __syncthreads();

    // GEMM1: h_pre[16][128] = xi @ W1slice + bias1
    f32x4 acc1[2];
#pragma unroll
    for (int tt = 0; tt < 2; ++tt) {
      const float bb = sbias1[(2 * w + tt) * 16 + n16];
      acc1[tt] = (f32x4){bb, bb, bb, bb};
    }
#pragma unroll
    for (int kk = 0; kk < 8; ++kk) {
      const f16x8 av = *(const f16x8*)(xi_s + n16 * 264 + kk * 32 + q * 8);
#pragma unroll
      for (int tt = 0; tt < 2; ++tt) {
        const f16x8 bv =
            *(const f16x8*)(W1s + ((2 * w + tt) * 16 + n16) * 264 + kk * 32 + q * 8);
        acc1[tt] = __builtin_amdgcn_mfma_f32_16x16x32_f16(av, bv, acc1[tt], 0, 0, 0);
      }
    }
#pragma unroll
    for (int tt = 0; tt < 2; ++tt) {
      const int c = (2 * w + tt) * 16 + n16;
#pragma unroll
      for (int reg = 0; reg < 4; ++reg)
        h_s[(q * 4 + reg) * 136 + c] = (_Float16)fast_tanh(acc1[tt][reg]);
    }
    __syncthreads();

    // GEMM2 partial: kp[16][256] = h @ W2slice (bias added by reader)
    f32x4 acc2[4];
#pragma unroll
    for (int tt = 0; tt < 4; ++tt) acc2[tt] = (f32x4){0.f, 0.f, 0.f, 0.f};
#pragma unroll
    for (int kk = 0; kk < 4; ++kk) {
      const f16x8 av = *(const f16x8*)(h_s + n16 * 136 + kk * 32 + q * 8);
#pragma unroll
      for (int tt = 0; tt < 4; ++tt) {
        const f16x8 bv =
            *(const f16x8*)(W2s + ((w * 4 + tt) * 16 + n16) * 136 + kk * 32 + q * 8);
        acc2[tt] = __builtin_amdgcn_mfma_f32_16x16x32_f16(av, bv, acc2[tt], 0, 0, 0);
      }
    }
    // transpose fragments -> row-major f16 staging in LDS (reuse xi_s rows0-7)
    _Float16* stag = xi_s;
    if (q < 2) {
#pragma unroll
      for (int tt = 0; tt < 4; ++tt) {
        const int c = (w * 4 + tt) * 16 + n16;
#pragma unroll
        for (int reg = 0; reg < 4; ++reg)
          stag[(q * 4 + reg) * 264 + c] = (_Float16)acc2[tt][reg];
      }
    }
    __syncthreads();
    // publish: 16 B per thread, relaxed agent stores (write-through, no fence)
    {
      const unsigned long long* srcp =
          (const unsigned long long*)(stag + r * 264 + fb * 8);
      unsigned long long u0 = srcp[0], u1 = srcp[1];
      unsigned long long* dst =
          partB + (buf << 17) + (bx << 9) + (r << 6) + (fb << 1);
      __hip_atomic_store(dst, u0, __ATOMIC_RELAXED, __HIP_MEMORY_SCOPE_AGENT);
      __hip_atomic_store(dst + 1, u1, __ATOMIC_RELAXED, __HIP_MEMORY_SCOPE_AGENT);
    }
    __syncthreads();  // vmcnt(0) per wave: all WG data stores acked/visible
    // stamp: visibility of (stamp == phase) implies this member's data is
    // visible (data stores were drained before the stamp store issued).
    if (tid == 0)
      __hip_atomic_store(&stamps[g * 16 + m], phase, __ATOMIC_RELAXED,
                         __HIP_MEMORY_SCOPE_AGENT);
    // wave 0, lanes 0..7 poll the group's 8-stamp line; retries paced by
    // s_sleep to keep speculative poll loads off the coherence point.
    if (w == 0) {
      for (;;) {
        unsigned v = phase;
        if (lane < 8)
          v = __hip_atomic_load(&stamps[g * 16 + lane], __ATOMIC_RELAXED,
                                __HIP_MEMORY_SCOPE_AGENT);
        if (__all(v >= phase)) break;
        __builtin_amdgcn_s_sleep(4);  // ~256 cyc backoff
      }
    }
    __syncthreads();
    // gather + reduce 8 members' f16 partials (+b2), relaxed agent loads
    float kacc[8];
    {
      const float4* sb2v = (const float4*)(sb2 + fb * 8);
      float4 bA = sb2v[0], bB = sb2v[1];
      kacc[0] = bA.x; kacc[1] = bA.y; kacc[2] = bA.z; kacc[3] = bA.w;
      kacc[4] = bB.x; kacc[5] = bB.y; kacc[6] = bB.z; kacc[7] = bB.w;
    }
    const int gbase = (buf << 17) + (r << 6) + (fb << 1);
#pragma unroll
    for (int mm = 0; mm < 8; ++mm) {
      const unsigned long long* pp = partB + gbase + ((mm * 32 + g) << 9);
      U64H4 ua, ub;
      ua.u = __hip_atomic_load(pp, __ATOMIC_RELAXED, __HIP_MEMORY_SCOPE_AGENT);
      ub.u = __hip_atomic_load(pp + 1, __ATOMIC_RELAXED, __HIP_MEMORY_SCOPE_AGENT);
#pragma unroll
      for (int j = 0; j < 4; ++j) {
        kacc[j] += (float)ua.h[j];
        kacc[4 + j] += (float)ub.h[j];
      }
    }
#pragma unroll
    for (int j = 0; j < 8; ++j) kout[j] = kacc[j];
  };

  // ---- Butcher tableau ----------------------------------------------------
  const float AB[6][6] = {
      {(float)(1.0 / 5.0), 0, 0, 0, 0, 0},
      {(float)(3.0 / 40.0), (float)(9.0 / 40.0), 0, 0, 0, 0},
      {(float)(44.0 / 45.0), (float)(-56.0 / 15.0), (float)(32.0 / 9.0), 0, 0, 0},
      {(float)(19372.0 / 6561.0), (float)(-25360.0 / 2187.0),
       (float)(64448.0 / 6561.0), (float)(-212.0 / 729.0), 0, 0},
      {(float)(9017.0 / 3168.0), (float)(-355.0 / 33.0),
       (float)(46732.0 / 5247.0), (float)(49.0 / 176.0),
       (float)(-5103.0 / 18656.0), 0},
      {(float)(35.0 / 384.0), 0.0f, (float)(500.0 / 1113.0),
       (float)(125.0 / 192.0), (float)(-2187.0 / 6784.0), (float)(11.0 / 84.0)}};
  const float CC[7] = {0.0f, (float)(1.0 / 5.0), (float)(3.0 / 10.0),
                       (float)(4.0 / 5.0), (float)(8.0 / 9.0), 1.0f, 1.0f};
  const float DD[7] = {(float)(35.0 / 384.0 - 5179.0 / 57600.0), 0.0f,
                       (float)(500.0 / 1113.0 - 7571.0 / 16695.0),
                       (float)(125.0 / 192.0 - 393.0 / 640.0),
                       (float)(-2187.0 / 6784.0 + 92097.0 / 339200.0),
                       (float)(11.0 / 84.0 - 187.0 / 2100.0),
                       (float)(-1.0 / 40.0)};

  float t = 0.0f, dt = 0.05f;
  stage_eval(x, 0.0f, ks[0]);  // FSAL seed

  for (int it = 0; it < 64; ++it) {
    if (t >= 1.0f) break;  // controller is globally uniform -> exact
    const float dt_c = fmaxf(fminf(dt, 1.0f - t), 0.0f);

    float x5[8];
#pragma unroll
    for (int s = 1; s <= 6; ++s) {
      float xi[8];
#pragma unroll
      for (int j = 0; j < 8; ++j) {
        float v = x[j];
#pragma unroll
        for (int p = 0; p < 6; ++p)
          if (p < s) v = fmaf(dt_c * AB[s - 1][p], ks[p][j], v);
        xi[j] = v;
        if (s == 6) x5[j] = v;  // stage-7 point == x5 (FSAL)
      }
      stage_eval(xi, fmaf(CC[s], dt_c, t), ks[s]);
    }

    // member 0 of each group publishes its group's err sum to a slot
    if (m == 0) {
      float loc = 0.0f;
#pragma unroll
      for (int j = 0; j < 8; ++j) {
        float e = 0.0f;
#pragma unroll
        for (int s = 0; s < 7; ++s) e = fmaf(dt_c * DD[s], ks[s][j], e);
        const float scale = fmaf(1e-3f, fmaxf(fabsf(x[j]), fabsf(x5[j])), 1e-4f);
        const float rr = e / scale;
        loc = fmaf(rr, rr, loc);
      }
#pragma unroll
      for (int o = 32; o > 0; o >>= 1) loc += __shfl_down(loc, o);
      if (lane == 0) sred[w] = loc;
      __syncthreads();
      if (tid == 0) {
        const float s4 = sred[0] + sred[1] + sred[2] + sred[3];
        __hip_atomic_store(&errSlots[it * 32 + g], s4, __ATOMIC_RELAXED,
                           __HIP_MEMORY_SCOPE_AGENT);
      }
    }
    // wave 0 polls the 32 slots (sentinel: poison/init negative); paced retry
    if (w == 0) {
      for (;;) {
        float v = 0.0f;
        bool okl = true;
        if (lane < 32) {
          v = __hip_atomic_load(&errSlots[it * 32 + lane], __ATOMIC_RELAXED,
                                __HIP_MEMORY_SCOPE_AGENT);
          okl = (v >= 0.0f);
        }
        if (__all(okl)) {
#pragma unroll
          for (int o = 32; o > 0; o >>= 1) v += __shfl_down(v, o);
          if (lane == 0) sbc[0] = v;
          break;
        }
        __builtin_amdgcn_s_sleep(4);  // ~256 cyc backoff
      }
    }
    __syncthreads();
    const float total = sbc[0];
    const float err_norm = sqrtf(total * (1.0f / 65536.0f));
    const bool accept = err_norm <= 1.0f;
    float factor = 0.9f * powf(err_norm + 1e-10f, -0.2f);
    factor = fminf(fmaxf(factor, 0.2f), 5.0f);
    if (accept) {
      t = t + dt_c;
#pragma unroll
      for (int j = 0; j < 8; ++j) { x[j] = x5[j]; ks[0][j] = ks[6][j]; }
    }
    dt = dt_c * factor;
  }

  // ---- output: stack([x0, xf]) (member 0 only) ---------------------------
  if (m == 0) {
    float4* o0 = (float4*)(out + (8 * g + r) * 256 + fb * 8);
    const float4* xr = (const float4*)xrow;
    o0[0] = xr[0]; o0[1] = xr[1];
    float4 a0, a1;
    a0.x = x[0]; a0.y = x[1]; a0.z = x[2]; a0.w = x[3];
    a1.x = x[4]; a1.y = x[5]; a1.z = x[6]; a1.w = x[7];
    float4* o1 = (float4*)(out + 65536 + (8 * g + r) * 256 + fb * 8);
    o1[0] = a0; o1[1] = a1;
  }
}

extern "C" void kernel_launch(void* const* d_in, const int* in_sizes, int n_in,
                              void* d_out, int out_size, void* d_ws,
                              size_t ws_size, hipStream_t stream) {
  const float* x0 = (const float*)d_in[0];
  const float* W1 = (const float*)d_in[1];
  const float* b1 = (const float*)d_in[2];
  const float* W2 = (const float*)d_in[3];
  const float* b2 = (const float*)d_in[4];
  float* out = (float*)d_out;
  char* ws = (char*)d_ws;
  unsigned long long* partB = (unsigned long long*)ws;
  unsigned* stamps = (unsigned*)(ws + STAMP_OFF);
  float* errSlots = (float*)(ws + SLOT_OFF);

  hipFuncSetAttribute((const void*)neural_ode_dopri5,
                      hipFuncAttributeMaxDynamicSharedMemorySize, SMEM_BYTES);

  void* args[] = {&x0, &W1, &b1, &W2, &b2, &out, &partB, &stamps, &errSlots};
  hipLaunchCooperativeKernel((void*)neural_ode_dopri5, dim3(256), dim3(256),
                             args, SMEM_BYTES, stream);
}